// Round 5
// baseline (696.122 us; speedup 1.0000x reference)
//
#include <hip/hip_runtime.h>
#include <hip/hip_bf16.h>
#include <math.h>

// Problem constants (fixed by reference)
#define N_NODES   40000
#define F1        256        // F_IN
#define F2        512        // F_OUT2
#define NEDGE     320000
#define NB        4          // batch (graphs)
#define PROTS     10000      // nodes per graph
#define G1DIM     1028
#define G2DIM     32
#define NDRUGS    640
#define ZDIM      (G2DIM + NDRUGS)   // 672

// ---------------------------------------------------------------------------
// CSC build: in-degree count -> exclusive scan -> bucket fill
// ---------------------------------------------------------------------------
__global__ void zero_cnt_kernel(int* __restrict__ cnt) {
    int i = blockIdx.x * blockDim.x + threadIdx.x;
    if (i < N_NODES) cnt[i] = 0;
}

__global__ void count_kernel(const int* __restrict__ cols, int* __restrict__ cnt) {
    int e = blockIdx.x * blockDim.x + threadIdx.x;
    if (e < NEDGE) atomicAdd(&cnt[cols[e]], 1);
}

// single block, 1024 threads: exclusive scan of cnt -> offsets & cursor,
// dinv = rsqrt(cnt+1), zero the pool buffer
__global__ __launch_bounds__(1024)
void scan_dinv_kernel(const int* __restrict__ cnt, int* __restrict__ offsets,
                      int* __restrict__ cursor, float* __restrict__ dinv,
                      float* __restrict__ pool) {
    __shared__ int wsum[16];
    __shared__ int wpre[16];
    __shared__ int s_running;
    int t = threadIdx.x, lane = t & 63, wid = t >> 6;
    if (t == 0) s_running = 0;
    __syncthreads();
    for (int base = 0; base < N_NODES; base += 1024) {
        int i = base + t;
        int v = (i < N_NODES) ? cnt[i] : 0;
        if (i < N_NODES) dinv[i] = rsqrtf((float)v + 1.0f);
        // wave-inclusive scan
        int s = v;
#pragma unroll
        for (int off = 1; off < 64; off <<= 1) {
            int u = __shfl_up(s, off);
            if (lane >= off) s += u;
        }
        if (lane == 63) wsum[wid] = s;
        __syncthreads();
        if (t < 16) {
            int a = wsum[t];
            int p = a;
#pragma unroll
            for (int off = 1; off < 16; off <<= 1) {
                int u = __shfl_up(p, off);
                if (t >= off) p += u;
            }
            wpre[t] = p - a;   // exclusive across waves
        }
        __syncthreads();
        int excl = s_running + wpre[wid] + (s - v);
        if (i < N_NODES) { offsets[i] = excl; cursor[i] = excl; }
        __syncthreads();                 // all reads of s_running done
        if (t == 1023) s_running = excl + v;
        __syncthreads();
    }
    if (t == 0) offsets[N_NODES] = s_running;   // == NEDGE
    for (int i = t; i < NB * F2; i += 1024) pool[i] = 0.0f;
}

__global__ void fill_kernel(const int* __restrict__ rows, const int* __restrict__ cols,
                            int* __restrict__ cursor, int* __restrict__ row_sorted) {
    int e = blockIdx.x * blockDim.x + threadIdx.x;
    if (e < NEDGE) {
        int pos = atomicAdd(&cursor[cols[e]], 1);
        row_sorted[pos] = rows[e];
    }
}

// ---------------------------------------------------------------------------
// fp32 tiled GEMM:  C[M,N] = (RELU_A ? relu(A) : A) @ W,  A[M,K], W[K,N]
// BM=64 BN=256 BK=16, 256 threads, 4x16 acc per thread.
// 64 FMA per thread per k vs 5 ds_read_b128 -> VALU-bound by design.
// Requires M%64==0, N%256==0, K%16==0.
// ---------------------------------------------------------------------------
template <bool RELU_A>
__global__ __launch_bounds__(256)
void gemm_kernel(const float* __restrict__ A, const float* __restrict__ W,
                 float* __restrict__ C, int M, int K, int N) {
    constexpr int BM = 64, BN = 256, BK = 16;
    __shared__ float As[BK][BM + 4];   // +4 pad keeps 16B align, breaks store conflicts
    __shared__ float Ws[BK][BN];

    const int t  = threadIdx.x;
    const int m0 = blockIdx.x * BM;
    const int n0 = blockIdx.y * BN;

    const int tr = (t >> 4) * 4;       // 4 output rows
    const int tc = (t & 15) * 4;       // cols tc + {0,64,128,192}

    float acc[4][16];
#pragma unroll
    for (int i = 0; i < 4; ++i)
#pragma unroll
        for (int j = 0; j < 16; ++j) acc[i][j] = 0.0f;

    // global load assignment
    const int la_row = t >> 2;          // 0..63
    const int la_col = (t & 3) * 4;     // 0,4,8,12
    const int lw_row = t >> 4;          // 0..15
    const int lw_col = (t & 15) * 4;    // 0..60 (+64/128/192)

    const float* Aptr = A + (size_t)(m0 + la_row) * K + la_col;
    const float* Wptr = W + (size_t)lw_row * N + n0 + lw_col;

    for (int k0 = 0; k0 < K; k0 += BK) {
        float4 av = *(const float4*)Aptr;  Aptr += BK;
        if (RELU_A) {
            av.x = fmaxf(av.x, 0.0f); av.y = fmaxf(av.y, 0.0f);
            av.z = fmaxf(av.z, 0.0f); av.w = fmaxf(av.w, 0.0f);
        }
        float4 wv0 = *(const float4*)(Wptr + 0);
        float4 wv1 = *(const float4*)(Wptr + 64);
        float4 wv2 = *(const float4*)(Wptr + 128);
        float4 wv3 = *(const float4*)(Wptr + 192);
        Wptr += (size_t)BK * N;

        As[la_col + 0][la_row] = av.x;
        As[la_col + 1][la_row] = av.y;
        As[la_col + 2][la_row] = av.z;
        As[la_col + 3][la_row] = av.w;
        *(float4*)&Ws[lw_row][lw_col +   0] = wv0;
        *(float4*)&Ws[lw_row][lw_col +  64] = wv1;
        *(float4*)&Ws[lw_row][lw_col + 128] = wv2;
        *(float4*)&Ws[lw_row][lw_col + 192] = wv3;
        __syncthreads();

#pragma unroll
        for (int k = 0; k < BK; ++k) {
            float4 a  = *(const float4*)&As[k][tr];
            float4 w0 = *(const float4*)&Ws[k][tc +   0];
            float4 w1 = *(const float4*)&Ws[k][tc +  64];
            float4 w2 = *(const float4*)&Ws[k][tc + 128];
            float4 w3 = *(const float4*)&Ws[k][tc + 192];
            float ar[4] = {a.x, a.y, a.z, a.w};
            float wr[16] = {w0.x, w0.y, w0.z, w0.w, w1.x, w1.y, w1.z, w1.w,
                            w2.x, w2.y, w2.z, w2.w, w3.x, w3.y, w3.z, w3.w};
#pragma unroll
            for (int i = 0; i < 4; ++i)
#pragma unroll
                for (int j = 0; j < 16; ++j)
                    acc[i][j] = fmaf(ar[i], wr[j], acc[i][j]);
        }
        __syncthreads();
    }

#pragma unroll
    for (int i = 0; i < 4; ++i) {
        size_t row = (size_t)(m0 + tr + i);
        float* cp = &C[row * N + n0 + tc];
        *(float4*)(cp +   0) = make_float4(acc[i][ 0], acc[i][ 1], acc[i][ 2], acc[i][ 3]);
        *(float4*)(cp +  64) = make_float4(acc[i][ 4], acc[i][ 5], acc[i][ 6], acc[i][ 7]);
        *(float4*)(cp + 128) = make_float4(acc[i][ 8], acc[i][ 9], acc[i][10], acc[i][11]);
        *(float4*)(cp + 192) = make_float4(acc[i][12], acc[i][13], acc[i][14], acc[i][15]);
    }
}

// ---------------------------------------------------------------------------
// CSC gather: one block per destination node.
//   agg[c] = (h[c]*dinv[c] + sum_{r in N(c)} h[r]*dinv[r]) * dinv[c] + bias
// block = C/4 threads, float4 per thread, no atomics.
// 4-deep unroll: 4 outstanding row loads to hide L2/L3 latency.
// ---------------------------------------------------------------------------
template <int C>
__global__ __launch_bounds__(C / 4)
void gather_kernel(const float* __restrict__ h, const float* __restrict__ dinv,
                   const int* __restrict__ offsets, const int* __restrict__ row_sorted,
                   const float* __restrict__ bias, float* __restrict__ agg) {
    const int c = blockIdx.x;
    const int t = threadIdx.x;
    const float dc = dinv[c];

    float4 v = ((const float4*)(h + (size_t)c * C))[t];
    float4 acc;
    acc.x = v.x * dc; acc.y = v.y * dc; acc.z = v.z * dc; acc.w = v.w * dc;

    const int beg = offsets[c], end = offsets[c + 1];
    int j = beg;
    for (; j + 4 <= end; j += 4) {
        int r0 = row_sorted[j + 0];
        int r1 = row_sorted[j + 1];
        int r2 = row_sorted[j + 2];
        int r3 = row_sorted[j + 3];
        float d0 = dinv[r0], d1 = dinv[r1], d2 = dinv[r2], d3 = dinv[r3];
        float4 u0 = ((const float4*)(h + (size_t)r0 * C))[t];
        float4 u1 = ((const float4*)(h + (size_t)r1 * C))[t];
        float4 u2 = ((const float4*)(h + (size_t)r2 * C))[t];
        float4 u3 = ((const float4*)(h + (size_t)r3 * C))[t];
        acc.x = fmaf(u0.x, d0, acc.x); acc.y = fmaf(u0.y, d0, acc.y);
        acc.z = fmaf(u0.z, d0, acc.z); acc.w = fmaf(u0.w, d0, acc.w);
        acc.x = fmaf(u1.x, d1, acc.x); acc.y = fmaf(u1.y, d1, acc.y);
        acc.z = fmaf(u1.z, d1, acc.z); acc.w = fmaf(u1.w, d1, acc.w);
        acc.x = fmaf(u2.x, d2, acc.x); acc.y = fmaf(u2.y, d2, acc.y);
        acc.z = fmaf(u2.z, d2, acc.z); acc.w = fmaf(u2.w, d2, acc.w);
        acc.x = fmaf(u3.x, d3, acc.x); acc.y = fmaf(u3.y, d3, acc.y);
        acc.z = fmaf(u3.z, d3, acc.z); acc.w = fmaf(u3.w, d3, acc.w);
    }
    for (; j < end; ++j) {
        int r0 = row_sorted[j];
        float d0 = dinv[r0];
        float4 u0 = ((const float4*)(h + (size_t)r0 * C))[t];
        acc.x = fmaf(u0.x, d0, acc.x); acc.y = fmaf(u0.y, d0, acc.y);
        acc.z = fmaf(u0.z, d0, acc.z); acc.w = fmaf(u0.w, d0, acc.w);
    }

    float4 b = ((const float4*)bias)[t];
    float4 o;
    o.x = fmaf(acc.x, dc, b.x);
    o.y = fmaf(acc.y, dc, b.y);
    o.z = fmaf(acc.z, dc, b.z);
    o.w = fmaf(acc.w, dc, b.w);
    ((float4*)(agg + (size_t)c * C))[t] = o;
}

// ---------------------------------------------------------------------------
// max-pool over nodes per graph, fused relu (seed m=0: relu(max)==max(relu)).
// grid: (F2/256, NCHUNK, NB), block 256
// ---------------------------------------------------------------------------
#define NCHUNK 100
__global__ __launch_bounds__(256)
void pool_kernel(const float* __restrict__ agg2, unsigned int* __restrict__ pool) {
    int f = blockIdx.x * 256 + threadIdx.x;
    int b = blockIdx.z;
    int chunk = blockIdx.y;
    const int npc = PROTS / NCHUNK;                 // 100
    const float* p = agg2 + ((size_t)(b * PROTS + chunk * npc)) * F2 + f;
    float m = 0.0f;
    for (int n = 0; n < npc; ++n) m = fmaxf(m, p[(size_t)n * F2]);
    atomicMax(&pool[b * F2 + f], __float_as_uint(m));
}

// ---------------------------------------------------------------------------
// g1 = relu(pool @ Wg1 + bg1)   [4,512]@[512,1028]
// ---------------------------------------------------------------------------
__global__ void mlpg1_kernel(const float* __restrict__ pool, const float* __restrict__ Wg1,
                             const float* __restrict__ bg1, float* __restrict__ out) {
    int idx = blockIdx.x * blockDim.x + threadIdx.x;
    if (idx >= NB * G1DIM) return;
    int b = idx / G1DIM, j = idx % G1DIM;
    const float* g = pool + b * F2;
    float s0 = 0.f, s1 = 0.f, s2 = 0.f, s3 = 0.f;
    for (int k = 0; k < F2; k += 4) {
        s0 = fmaf(g[k + 0], Wg1[(size_t)(k + 0) * G1DIM + j], s0);
        s1 = fmaf(g[k + 1], Wg1[(size_t)(k + 1) * G1DIM + j], s1);
        s2 = fmaf(g[k + 2], Wg1[(size_t)(k + 2) * G1DIM + j], s2);
        s3 = fmaf(g[k + 3], Wg1[(size_t)(k + 3) * G1DIM + j], s3);
    }
    out[idx] = fmaxf((s0 + s1) + (s2 + s3) + bg1[j], 0.0f);
}

// ---------------------------------------------------------------------------
// tail: g2 = g1@Wg2+bg2 ; z=[g2,DDI] ; f1=relu(z@Wf1+bf1) ;
//       f2=relu(f1@Wf2+bf2) ; out=sigmoid(f2@Wf3+bf3)      single block
// ---------------------------------------------------------------------------
__global__ __launch_bounds__(256)
void tail_kernel(const float* __restrict__ g1, const float* __restrict__ Wg2,
                 const float* __restrict__ bg2, const float* __restrict__ DDI,
                 const float* __restrict__ Wf1, const float* __restrict__ bf1,
                 const float* __restrict__ Wf2, const float* __restrict__ bf2,
                 const float* __restrict__ Wf3, const float* __restrict__ bf3,
                 float* __restrict__ out) {
    __shared__ float zs[NB][ZDIM + 8];
    __shared__ float f1s[NB][64];
    __shared__ float f2s[NB][16];
    int t = threadIdx.x;

    if (t < NB * G2DIM) {                      // 128 threads: g2
        int b = t >> 5, j = t & 31;
        float s0 = 0.f, s1 = 0.f, s2 = 0.f, s3 = 0.f;
        const float* gp = g1 + b * G1DIM;
        int k = 0;
        for (; k + 4 <= G1DIM; k += 4) {
            s0 = fmaf(gp[k + 0], Wg2[(size_t)(k + 0) * G2DIM + j], s0);
            s1 = fmaf(gp[k + 1], Wg2[(size_t)(k + 1) * G2DIM + j], s1);
            s2 = fmaf(gp[k + 2], Wg2[(size_t)(k + 2) * G2DIM + j], s2);
            s3 = fmaf(gp[k + 3], Wg2[(size_t)(k + 3) * G2DIM + j], s3);
        }
        for (; k < G1DIM; ++k) s0 = fmaf(gp[k], Wg2[(size_t)k * G2DIM + j], s0);
        zs[b][j] = (s0 + s1) + (s2 + s3) + bg2[j];
    }
    for (int i = t; i < NB * NDRUGS; i += 256) {
        int b = i / NDRUGS, k = i % NDRUGS;
        zs[b][G2DIM + k] = DDI[i];
    }
    __syncthreads();

    {   // f1: all 256 threads
        int b = t >> 6, j = t & 63;
        float s = bf1[j];
        for (int k = 0; k < ZDIM; ++k) s = fmaf(zs[b][k], Wf1[(size_t)k * 64 + j], s);
        f1s[b][j] = fmaxf(s, 0.0f);
    }
    __syncthreads();

    if (t < NB * 16) {
        int b = t >> 4, j = t & 15;
        float s = bf2[j];
#pragma unroll
        for (int k = 0; k < 64; ++k) s = fmaf(f1s[b][k], Wf2[k * 16 + j], s);
        f2s[b][j] = fmaxf(s, 0.0f);
    }
    __syncthreads();

    if (t < NB) {
        float s = bf3[0];
#pragma unroll
        for (int k = 0; k < 16; ++k) s = fmaf(f2s[t][k], Wf3[k], s);
        out[t] = 1.0f / (1.0f + expf(-s));
    }
}

// ---------------------------------------------------------------------------
// launch
// ---------------------------------------------------------------------------
extern "C" void kernel_launch(void* const* d_in, const int* in_sizes, int n_in,
                              void* d_out, int out_size, void* d_ws, size_t ws_size,
                              hipStream_t stream) {
    const float* x   = (const float*)d_in[0];
    const int*   ei  = (const int*)d_in[1];
    const float* DDI = (const float*)d_in[2];
    const float* W1  = (const float*)d_in[3];
    const float* b1  = (const float*)d_in[4];
    const float* W2  = (const float*)d_in[5];
    const float* b2  = (const float*)d_in[6];
    const float* Wg1 = (const float*)d_in[7];
    const float* bg1 = (const float*)d_in[8];
    const float* Wg2 = (const float*)d_in[9];
    const float* bg2 = (const float*)d_in[10];
    const float* Wf1 = (const float*)d_in[11];
    const float* bf1 = (const float*)d_in[12];
    const float* Wf2 = (const float*)d_in[13];
    const float* bf2 = (const float*)d_in[14];
    const float* Wf3 = (const float*)d_in[15];
    const float* bf3 = (const float*)d_in[16];
    float* out = (float*)d_out;

    const int* rows = ei;            // edge_index[0]
    const int* cols = ei + NEDGE;    // edge_index[1]

    // workspace layout
    char* ws = (char*)d_ws;
    const size_t MiB = 1024 * 1024;
    int*   cnt        = (int*)(ws + 0);            // 160 KB
    int*   offsets    = (int*)(ws + 256 * 1024);   // 160 KB (+1 elem)
    int*   cursor     = (int*)(ws + 512 * 1024);   // 160 KB
    float* dinv       = (float*)(ws + 768 * 1024); // 160 KB
    int*   row_sorted = (int*)(ws + 1 * MiB);      // 1.28 MB
    float* pool       = (float*)(ws + 2560 * 1024);// 8 KB
    float* g1o        = (float*)(ws + 2664 * 1024);// 16.4 KB
    float* h1   = (float*)(ws + 4 * MiB);          // 40.96 MB  (ends ~43.1 MiB)
    float* agg1 = (float*)(ws + 44 * MiB);         // 40.96 MB  (ends ~83.1 MiB)
    float* h2   = (float*)(ws + 84 * MiB);         // 81.92 MB  (ends ~162.2 MiB)
    float* agg2 = (float*)(ws + 4 * MiB);          // reuses dead h1+agg1 region (ends ~82.1 MiB)

    // CSC build (shared by both conv layers)
    zero_cnt_kernel<<<(N_NODES + 255) / 256, 256, 0, stream>>>(cnt);
    count_kernel<<<(NEDGE + 255) / 256, 256, 0, stream>>>(cols, cnt);
    scan_dinv_kernel<<<1, 1024, 0, stream>>>(cnt, offsets, cursor, dinv, pool);
    fill_kernel<<<(NEDGE + 255) / 256, 256, 0, stream>>>(rows, cols, cursor, row_sorted);

    // conv1
    gemm_kernel<false><<<dim3(N_NODES / 64, F1 / 256), 256, 0, stream>>>(x, W1, h1, N_NODES, F1, F1);
    gather_kernel<F1><<<N_NODES, F1 / 4, 0, stream>>>(h1, dinv, offsets, row_sorted, b1, agg1);

    // conv2 (relu of conv1 fused into GEMM A-load)
    gemm_kernel<true><<<dim3(N_NODES / 64, F2 / 256), 256, 0, stream>>>(agg1, W2, h2, N_NODES, F1, F2);
    gather_kernel<F2><<<N_NODES, F2 / 4, 0, stream>>>(h2, dinv, offsets, row_sorted, b2, agg2);

    // pool (relu fused: max with 0)
    pool_kernel<<<dim3(F2 / 256, NCHUNK, NB), 256, 0, stream>>>(agg2, (unsigned int*)pool);

    // graph MLP + head
    mlpg1_kernel<<<(NB * G1DIM + 255) / 256, 256, 0, stream>>>(pool, Wg1, bg1, g1o);
    tail_kernel<<<1, 256, 0, stream>>>(g1o, Wg2, bg2, DDI, Wf1, bf1, Wf2, bf2, Wf3, bf3, out);
}

// Round 6
// 568.576 us; speedup vs baseline: 1.2243x; 1.2243x over previous
//
#include <hip/hip_runtime.h>
#include <hip/hip_bf16.h>
#include <math.h>

// Problem constants (fixed by reference)
#define N_NODES   40000
#define F1        256        // F_IN
#define F2        512        // F_OUT2
#define NEDGE     320000
#define NB        4          // batch (graphs)
#define PROTS     10000      // nodes per graph
#define G1DIM     1028
#define G2DIM     32
#define NDRUGS    640
#define ZDIM      (G2DIM + NDRUGS)   // 672

// ---------------------------------------------------------------------------
// CSC build: in-degree count -> exclusive scan -> bucket fill
// ---------------------------------------------------------------------------
__global__ void zero_cnt_kernel(int* __restrict__ cnt) {
    int i = blockIdx.x * blockDim.x + threadIdx.x;
    if (i < N_NODES) cnt[i] = 0;
}

__global__ void count_kernel(const int* __restrict__ cols, int* __restrict__ cnt) {
    int e = blockIdx.x * blockDim.x + threadIdx.x;
    if (e < NEDGE) atomicAdd(&cnt[cols[e]], 1);
}

// single block, 1024 threads: exclusive scan of cnt -> offsets & cursor,
// dinv = rsqrt(cnt+1), zero the pool buffer
__global__ __launch_bounds__(1024)
void scan_dinv_kernel(const int* __restrict__ cnt, int* __restrict__ offsets,
                      int* __restrict__ cursor, float* __restrict__ dinv,
                      float* __restrict__ pool) {
    __shared__ int wsum[16];
    __shared__ int wpre[16];
    __shared__ int s_running;
    int t = threadIdx.x, lane = t & 63, wid = t >> 6;
    if (t == 0) s_running = 0;
    __syncthreads();
    for (int base = 0; base < N_NODES; base += 1024) {
        int i = base + t;
        int v = (i < N_NODES) ? cnt[i] : 0;
        if (i < N_NODES) dinv[i] = rsqrtf((float)v + 1.0f);
        // wave-inclusive scan
        int s = v;
#pragma unroll
        for (int off = 1; off < 64; off <<= 1) {
            int u = __shfl_up(s, off);
            if (lane >= off) s += u;
        }
        if (lane == 63) wsum[wid] = s;
        __syncthreads();
        if (t < 16) {
            int a = wsum[t];
            int p = a;
#pragma unroll
            for (int off = 1; off < 16; off <<= 1) {
                int u = __shfl_up(p, off);
                if (t >= off) p += u;
            }
            wpre[t] = p - a;   // exclusive across waves
        }
        __syncthreads();
        int excl = s_running + wpre[wid] + (s - v);
        if (i < N_NODES) { offsets[i] = excl; cursor[i] = excl; }
        __syncthreads();                 // all reads of s_running done
        if (t == 1023) s_running = excl + v;
        __syncthreads();
    }
    if (t == 0) offsets[N_NODES] = s_running;   // == NEDGE
    for (int i = t; i < NB * F2; i += 1024) pool[i] = 0.0f;
}

__global__ void fill_kernel(const int* __restrict__ rows, const int* __restrict__ cols,
                            int* __restrict__ cursor, int* __restrict__ row_sorted) {
    int e = blockIdx.x * blockDim.x + threadIdx.x;
    if (e < NEDGE) {
        int pos = atomicAdd(&cursor[cols[e]], 1);
        row_sorted[pos] = rows[e];
    }
}

// ---------------------------------------------------------------------------
// CSC gather (aggregation-first form): one block per destination node.
//   out[c] = (src[c]*dinv[c] + sum_{r in N(c)} src[r]*dinv[r]) * dinv[c]
// RELU: apply relu to each loaded src element (for layer-2's relu(agg1)).
// block = C/4 threads, float4 per thread, no atomics, 4-deep load unroll.
// ---------------------------------------------------------------------------
template <int C, bool RELU>
__global__ __launch_bounds__(C / 4)
void gather_kernel(const float* __restrict__ src, const float* __restrict__ dinv,
                   const int* __restrict__ offsets, const int* __restrict__ row_sorted,
                   float* __restrict__ out) {
    const int c = blockIdx.x;
    const int t = threadIdx.x;
    const float dc = dinv[c];

    float4 v = ((const float4*)(src + (size_t)c * C))[t];
    if (RELU) {
        v.x = fmaxf(v.x, 0.0f); v.y = fmaxf(v.y, 0.0f);
        v.z = fmaxf(v.z, 0.0f); v.w = fmaxf(v.w, 0.0f);
    }
    float4 acc;
    acc.x = v.x * dc; acc.y = v.y * dc; acc.z = v.z * dc; acc.w = v.w * dc;

    const int beg = offsets[c], end = offsets[c + 1];
    int j = beg;
    for (; j + 4 <= end; j += 4) {
        int r0 = row_sorted[j + 0];
        int r1 = row_sorted[j + 1];
        int r2 = row_sorted[j + 2];
        int r3 = row_sorted[j + 3];
        float d0 = dinv[r0], d1 = dinv[r1], d2 = dinv[r2], d3 = dinv[r3];
        float4 u0 = ((const float4*)(src + (size_t)r0 * C))[t];
        float4 u1 = ((const float4*)(src + (size_t)r1 * C))[t];
        float4 u2 = ((const float4*)(src + (size_t)r2 * C))[t];
        float4 u3 = ((const float4*)(src + (size_t)r3 * C))[t];
        if (RELU) {
            u0.x = fmaxf(u0.x, 0.0f); u0.y = fmaxf(u0.y, 0.0f);
            u0.z = fmaxf(u0.z, 0.0f); u0.w = fmaxf(u0.w, 0.0f);
            u1.x = fmaxf(u1.x, 0.0f); u1.y = fmaxf(u1.y, 0.0f);
            u1.z = fmaxf(u1.z, 0.0f); u1.w = fmaxf(u1.w, 0.0f);
            u2.x = fmaxf(u2.x, 0.0f); u2.y = fmaxf(u2.y, 0.0f);
            u2.z = fmaxf(u2.z, 0.0f); u2.w = fmaxf(u2.w, 0.0f);
            u3.x = fmaxf(u3.x, 0.0f); u3.y = fmaxf(u3.y, 0.0f);
            u3.z = fmaxf(u3.z, 0.0f); u3.w = fmaxf(u3.w, 0.0f);
        }
        acc.x = fmaf(u0.x, d0, acc.x); acc.y = fmaf(u0.y, d0, acc.y);
        acc.z = fmaf(u0.z, d0, acc.z); acc.w = fmaf(u0.w, d0, acc.w);
        acc.x = fmaf(u1.x, d1, acc.x); acc.y = fmaf(u1.y, d1, acc.y);
        acc.z = fmaf(u1.z, d1, acc.z); acc.w = fmaf(u1.w, d1, acc.w);
        acc.x = fmaf(u2.x, d2, acc.x); acc.y = fmaf(u2.y, d2, acc.y);
        acc.z = fmaf(u2.z, d2, acc.z); acc.w = fmaf(u2.w, d2, acc.w);
        acc.x = fmaf(u3.x, d3, acc.x); acc.y = fmaf(u3.y, d3, acc.y);
        acc.z = fmaf(u3.z, d3, acc.z); acc.w = fmaf(u3.w, d3, acc.w);
    }
    for (; j < end; ++j) {
        int r0 = row_sorted[j];
        float d0 = dinv[r0];
        float4 u0 = ((const float4*)(src + (size_t)r0 * C))[t];
        if (RELU) {
            u0.x = fmaxf(u0.x, 0.0f); u0.y = fmaxf(u0.y, 0.0f);
            u0.z = fmaxf(u0.z, 0.0f); u0.w = fmaxf(u0.w, 0.0f);
        }
        acc.x = fmaf(u0.x, d0, acc.x); acc.y = fmaf(u0.y, d0, acc.y);
        acc.z = fmaf(u0.z, d0, acc.z); acc.w = fmaf(u0.w, d0, acc.w);
    }

    float4 o;
    o.x = acc.x * dc; o.y = acc.y * dc; o.z = acc.z * dc; o.w = acc.w * dc;
    ((float4*)(out + (size_t)c * C))[t] = o;
}

// ---------------------------------------------------------------------------
// fp32 tiled GEMM:  BM=64 BN=256 BK=16, 256 threads, 4x16 acc per thread.
// EPI=0: C = A@W + bias                      (layer-1 output)
// EPI=1: pool[g][n] max= relu(A@W + bias)    (layer-2 fused with per-graph
//        max-pool; nothing stored to C — pool must be pre-zeroed)
// Requires M%64==0, N%256==0, K%16==0.
// ---------------------------------------------------------------------------
template <int EPI>
__global__ __launch_bounds__(256)
void gemm_kernel(const float* __restrict__ A, const float* __restrict__ W,
                 const float* __restrict__ bias, float* __restrict__ C,
                 unsigned int* __restrict__ pool, int M, int K, int N) {
    constexpr int BM = 64, BN = 256, BK = 16;
    __shared__ float As[BK][BM + 4];   // +4 pad keeps 16B align, breaks store conflicts
    __shared__ float Ws[BK][BN];

    const int t  = threadIdx.x;
    const int m0 = blockIdx.x * BM;
    const int n0 = blockIdx.y * BN;

    const int tr = (t >> 4) * 4;       // 4 output rows
    const int tc = (t & 15) * 4;       // cols tc + {0,64,128,192}

    float acc[4][16];
#pragma unroll
    for (int i = 0; i < 4; ++i)
#pragma unroll
        for (int j = 0; j < 16; ++j) acc[i][j] = 0.0f;

    // global load assignment
    const int la_row = t >> 2;          // 0..63
    const int la_col = (t & 3) * 4;     // 0,4,8,12
    const int lw_row = t >> 4;          // 0..15
    const int lw_col = (t & 15) * 4;    // 0..60 (+64/128/192)

    const float* Aptr = A + (size_t)(m0 + la_row) * K + la_col;
    const float* Wptr = W + (size_t)lw_row * N + n0 + lw_col;

    for (int k0 = 0; k0 < K; k0 += BK) {
        float4 av = *(const float4*)Aptr;  Aptr += BK;
        float4 wv0 = *(const float4*)(Wptr + 0);
        float4 wv1 = *(const float4*)(Wptr + 64);
        float4 wv2 = *(const float4*)(Wptr + 128);
        float4 wv3 = *(const float4*)(Wptr + 192);
        Wptr += (size_t)BK * N;

        As[la_col + 0][la_row] = av.x;
        As[la_col + 1][la_row] = av.y;
        As[la_col + 2][la_row] = av.z;
        As[la_col + 3][la_row] = av.w;
        *(float4*)&Ws[lw_row][lw_col +   0] = wv0;
        *(float4*)&Ws[lw_row][lw_col +  64] = wv1;
        *(float4*)&Ws[lw_row][lw_col + 128] = wv2;
        *(float4*)&Ws[lw_row][lw_col + 192] = wv3;
        __syncthreads();

#pragma unroll
        for (int k = 0; k < BK; ++k) {
            float4 a  = *(const float4*)&As[k][tr];
            float4 w0 = *(const float4*)&Ws[k][tc +   0];
            float4 w1 = *(const float4*)&Ws[k][tc +  64];
            float4 w2 = *(const float4*)&Ws[k][tc + 128];
            float4 w3 = *(const float4*)&Ws[k][tc + 192];
            float ar[4] = {a.x, a.y, a.z, a.w};
            float wr[16] = {w0.x, w0.y, w0.z, w0.w, w1.x, w1.y, w1.z, w1.w,
                            w2.x, w2.y, w2.z, w2.w, w3.x, w3.y, w3.z, w3.w};
#pragma unroll
            for (int i = 0; i < 4; ++i)
#pragma unroll
                for (int j = 0; j < 16; ++j)
                    acc[i][j] = fmaf(ar[i], wr[j], acc[i][j]);
        }
        __syncthreads();
    }

    // bias for this thread's 16 columns
    float bcol[16];
    {
        float4 b0 = *(const float4*)&bias[n0 + tc +   0];
        float4 b1 = *(const float4*)&bias[n0 + tc +  64];
        float4 b2 = *(const float4*)&bias[n0 + tc + 128];
        float4 b3 = *(const float4*)&bias[n0 + tc + 192];
        bcol[0]=b0.x; bcol[1]=b0.y; bcol[2]=b0.z; bcol[3]=b0.w;
        bcol[4]=b1.x; bcol[5]=b1.y; bcol[6]=b1.z; bcol[7]=b1.w;
        bcol[8]=b2.x; bcol[9]=b2.y; bcol[10]=b2.z; bcol[11]=b2.w;
        bcol[12]=b3.x; bcol[13]=b3.y; bcol[14]=b3.z; bcol[15]=b3.w;
    }

    if constexpr (EPI == 0) {
#pragma unroll
        for (int i = 0; i < 4; ++i) {
            size_t row = (size_t)(m0 + tr + i);
            float* cp = &C[row * N + n0 + tc];
            *(float4*)(cp +   0) = make_float4(acc[i][0]+bcol[0],  acc[i][1]+bcol[1],
                                               acc[i][2]+bcol[2],  acc[i][3]+bcol[3]);
            *(float4*)(cp +  64) = make_float4(acc[i][4]+bcol[4],  acc[i][5]+bcol[5],
                                               acc[i][6]+bcol[6],  acc[i][7]+bcol[7]);
            *(float4*)(cp + 128) = make_float4(acc[i][8]+bcol[8],  acc[i][9]+bcol[9],
                                               acc[i][10]+bcol[10],acc[i][11]+bcol[11]);
            *(float4*)(cp + 192) = make_float4(acc[i][12]+bcol[12],acc[i][13]+bcol[13],
                                               acc[i][14]+bcol[14],acc[i][15]+bcol[15]);
        }
    } else {
        // fused per-graph max-pool of relu(acc + bias); block spans <=2 graphs
        __shared__ unsigned int red[2][BN];
        for (int i = t; i < 2 * BN; i += 256) red[i >> 8][i & 255] = 0u;
        __syncthreads();

        const int g_lo = m0 / PROTS;
        const int slot_first = (m0 + tr) / PROTS - g_lo;
        const int slot_last  = (m0 + tr + 3) / PROTS - g_lo;

        if (slot_first == slot_last) {
            // all 4 rows in one graph: register-reduce then 16 LDS atomics
#pragma unroll
            for (int j = 0; j < 16; ++j) {
                float m = fmaxf(fmaxf(acc[0][j], acc[1][j]), fmaxf(acc[2][j], acc[3][j]));
                m = fmaxf(m + bcol[j], 0.0f);
                int lc = tc + (j >> 2) * 64 + (j & 3);
                atomicMax(&red[slot_first][lc], __float_as_uint(m));
            }
        } else {
#pragma unroll
            for (int i = 0; i < 4; ++i) {
                int slot = (m0 + tr + i) / PROTS - g_lo;
#pragma unroll
                for (int j = 0; j < 16; ++j) {
                    float m = fmaxf(acc[i][j] + bcol[j], 0.0f);
                    int lc = tc + (j >> 2) * 64 + (j & 3);
                    atomicMax(&red[slot][lc], __float_as_uint(m));
                }
            }
        }
        __syncthreads();

        const int straddle = ((m0 + BM - 1) / PROTS) != g_lo;
        for (int lc = t; lc < BN; lc += 256) {
            atomicMax(&pool[(size_t)g_lo * F2 + n0 + lc], red[0][lc]);
            if (straddle)
                atomicMax(&pool[(size_t)(g_lo + 1) * F2 + n0 + lc], red[1][lc]);
        }
    }
}

// ---------------------------------------------------------------------------
// g1 = relu(pool @ Wg1 + bg1)   [4,512]@[512,1028]
// ---------------------------------------------------------------------------
__global__ void mlpg1_kernel(const float* __restrict__ pool, const float* __restrict__ Wg1,
                             const float* __restrict__ bg1, float* __restrict__ out) {
    int idx = blockIdx.x * blockDim.x + threadIdx.x;
    if (idx >= NB * G1DIM) return;
    int b = idx / G1DIM, j = idx % G1DIM;
    const float* g = pool + b * F2;
    float s0 = 0.f, s1 = 0.f, s2 = 0.f, s3 = 0.f;
    for (int k = 0; k < F2; k += 4) {
        s0 = fmaf(g[k + 0], Wg1[(size_t)(k + 0) * G1DIM + j], s0);
        s1 = fmaf(g[k + 1], Wg1[(size_t)(k + 1) * G1DIM + j], s1);
        s2 = fmaf(g[k + 2], Wg1[(size_t)(k + 2) * G1DIM + j], s2);
        s3 = fmaf(g[k + 3], Wg1[(size_t)(k + 3) * G1DIM + j], s3);
    }
    out[idx] = fmaxf((s0 + s1) + (s2 + s3) + bg1[j], 0.0f);
}

// ---------------------------------------------------------------------------
// tail: g2 = g1@Wg2+bg2 ; z=[g2,DDI] ; f1=relu(z@Wf1+bf1) ;
//       f2=relu(f1@Wf2+bf2) ; out=sigmoid(f2@Wf3+bf3)      single block
// ---------------------------------------------------------------------------
__global__ __launch_bounds__(256)
void tail_kernel(const float* __restrict__ g1, const float* __restrict__ Wg2,
                 const float* __restrict__ bg2, const float* __restrict__ DDI,
                 const float* __restrict__ Wf1, const float* __restrict__ bf1,
                 const float* __restrict__ Wf2, const float* __restrict__ bf2,
                 const float* __restrict__ Wf3, const float* __restrict__ bf3,
                 float* __restrict__ out) {
    __shared__ float zs[NB][ZDIM + 8];
    __shared__ float f1s[NB][64];
    __shared__ float f2s[NB][16];
    int t = threadIdx.x;

    if (t < NB * G2DIM) {                      // 128 threads: g2
        int b = t >> 5, j = t & 31;
        float s0 = 0.f, s1 = 0.f, s2 = 0.f, s3 = 0.f;
        const float* gp = g1 + b * G1DIM;
        int k = 0;
        for (; k + 4 <= G1DIM; k += 4) {
            s0 = fmaf(gp[k + 0], Wg2[(size_t)(k + 0) * G2DIM + j], s0);
            s1 = fmaf(gp[k + 1], Wg2[(size_t)(k + 1) * G2DIM + j], s1);
            s2 = fmaf(gp[k + 2], Wg2[(size_t)(k + 2) * G2DIM + j], s2);
            s3 = fmaf(gp[k + 3], Wg2[(size_t)(k + 3) * G2DIM + j], s3);
        }
        for (; k < G1DIM; ++k) s0 = fmaf(gp[k], Wg2[(size_t)k * G2DIM + j], s0);
        zs[b][j] = (s0 + s1) + (s2 + s3) + bg2[j];
    }
    for (int i = t; i < NB * NDRUGS; i += 256) {
        int b = i / NDRUGS, k = i % NDRUGS;
        zs[b][G2DIM + k] = DDI[i];
    }
    __syncthreads();

    {   // f1: all 256 threads
        int b = t >> 6, j = t & 63;
        float s = bf1[j];
        for (int k = 0; k < ZDIM; ++k) s = fmaf(zs[b][k], Wf1[(size_t)k * 64 + j], s);
        f1s[b][j] = fmaxf(s, 0.0f);
    }
    __syncthreads();

    if (t < NB * 16) {
        int b = t >> 4, j = t & 15;
        float s = bf2[j];
#pragma unroll
        for (int k = 0; k < 64; ++k) s = fmaf(f1s[b][k], Wf2[k * 16 + j], s);
        f2s[b][j] = fmaxf(s, 0.0f);
    }
    __syncthreads();

    if (t < NB) {
        float s = bf3[0];
#pragma unroll
        for (int k = 0; k < 16; ++k) s = fmaf(f2s[t][k], Wf3[k], s);
        out[t] = 1.0f / (1.0f + expf(-s));
    }
}

// ---------------------------------------------------------------------------
// launch
// ---------------------------------------------------------------------------
extern "C" void kernel_launch(void* const* d_in, const int* in_sizes, int n_in,
                              void* d_out, int out_size, void* d_ws, size_t ws_size,
                              hipStream_t stream) {
    const float* x   = (const float*)d_in[0];
    const int*   ei  = (const int*)d_in[1];
    const float* DDI = (const float*)d_in[2];
    const float* W1  = (const float*)d_in[3];
    const float* b1  = (const float*)d_in[4];
    const float* W2  = (const float*)d_in[5];
    const float* b2  = (const float*)d_in[6];
    const float* Wg1 = (const float*)d_in[7];
    const float* bg1 = (const float*)d_in[8];
    const float* Wg2 = (const float*)d_in[9];
    const float* bg2 = (const float*)d_in[10];
    const float* Wf1 = (const float*)d_in[11];
    const float* bf1 = (const float*)d_in[12];
    const float* Wf2 = (const float*)d_in[13];
    const float* bf2 = (const float*)d_in[14];
    const float* Wf3 = (const float*)d_in[15];
    const float* bf3 = (const float*)d_in[16];
    float* out = (float*)d_out;

    const int* rows = ei;            // edge_index[0]
    const int* cols = ei + NEDGE;    // edge_index[1]

    // workspace layout
    char* ws = (char*)d_ws;
    const size_t MiB = 1024 * 1024;
    int*   cnt        = (int*)(ws + 0);            // 160 KB
    int*   offsets    = (int*)(ws + 256 * 1024);   // 160 KB (+1 elem)
    int*   cursor     = (int*)(ws + 512 * 1024);   // 160 KB
    float* dinv       = (float*)(ws + 768 * 1024); // 160 KB
    int*   row_sorted = (int*)(ws + 1 * MiB);      // 1.28 MB
    float* pool       = (float*)(ws + 2560 * 1024);// 8 KB
    float* g1o        = (float*)(ws + 2664 * 1024);// 16.4 KB
    float* xa   = (float*)(ws + 4 * MiB);          // 40.96 MB (aggregated x; later reused as ya)
    float* agg1 = (float*)(ws + 48 * MiB);         // 40.96 MB (ends ~88 MiB)
    float* ya   = xa;                              // xa dead after gemm1 -> reuse

    // CSC build (shared by both conv layers)
    zero_cnt_kernel<<<(N_NODES + 255) / 256, 256, 0, stream>>>(cnt);
    count_kernel<<<(NEDGE + 255) / 256, 256, 0, stream>>>(cols, cnt);
    scan_dinv_kernel<<<1, 1024, 0, stream>>>(cnt, offsets, cursor, dinv, pool);
    fill_kernel<<<(NEDGE + 255) / 256, 256, 0, stream>>>(rows, cols, cursor, row_sorted);

    // conv1, aggregation-first:  xa = A_hat x ;  agg1 = xa@W1 + b1
    gather_kernel<F1, false><<<N_NODES, F1 / 4, 0, stream>>>(x, dinv, offsets, row_sorted, xa);
    gemm_kernel<0><<<dim3(N_NODES / 64, F1 / 256), 256, 0, stream>>>(
        xa, W1, b1, agg1, nullptr, N_NODES, F1, F1);

    // conv2, aggregation-first:  ya = A_hat relu(agg1) ;
    // pool[g][:] = max over rows of relu(ya@W2 + b2)   (fused epilogue)
    gather_kernel<F1, true><<<N_NODES, F1 / 4, 0, stream>>>(agg1, dinv, offsets, row_sorted, ya);
    gemm_kernel<1><<<dim3(N_NODES / 64, F2 / 256), 256, 0, stream>>>(
        ya, W2, b2, nullptr, (unsigned int*)pool, N_NODES, F1, F2);

    // graph MLP + head
    mlpg1_kernel<<<(NB * G1DIM + 255) / 256, 256, 0, stream>>>(pool, Wg1, bg1, g1o);
    tail_kernel<<<1, 256, 0, stream>>>(g1o, Wg2, bg2, DDI, Wf1, bf1, Wf2, bf2, Wf3, bf3, out);
}

// Round 12
// 567.071 us; speedup vs baseline: 1.2276x; 1.0027x over previous
//
#include <hip/hip_runtime.h>
#include <hip/hip_bf16.h>
#include <math.h>

// Problem constants (fixed by reference)
#define N_NODES   40000
#define F1        256        // F_IN
#define F2        512        // F_OUT2
#define NEDGE     320000
#define NB        4          // batch (graphs)
#define PROTS     10000      // nodes per graph
#define G1DIM     1028
#define G2DIM     32
#define NDRUGS    640
#define ZDIM      (G2DIM + NDRUGS)   // 672

// ---------------------------------------------------------------------------
// CSC build: in-degree count -> exclusive scan -> bucket fill
// ---------------------------------------------------------------------------
__global__ void zero_cnt_kernel(int* __restrict__ cnt) {
    int i = blockIdx.x * blockDim.x + threadIdx.x;
    if (i < N_NODES) cnt[i] = 0;
}

__global__ void count_kernel(const int* __restrict__ cols, int* __restrict__ cnt) {
    int e = blockIdx.x * blockDim.x + threadIdx.x;
    if (e < NEDGE) atomicAdd(&cnt[cols[e]], 1);
}

// single block, 1024 threads: exclusive scan of cnt -> offsets & cursor,
// dinv = rsqrt(cnt+1), zero the pool buffer
__global__ __launch_bounds__(1024)
void scan_dinv_kernel(const int* __restrict__ cnt, int* __restrict__ offsets,
                      int* __restrict__ cursor, float* __restrict__ dinv,
                      float* __restrict__ pool) {
    __shared__ int wsum[16];
    __shared__ int wpre[16];
    __shared__ int s_running;
    int t = threadIdx.x, lane = t & 63, wid = t >> 6;
    if (t == 0) s_running = 0;
    __syncthreads();
    for (int base = 0; base < N_NODES; base += 1024) {
        int i = base + t;
        int v = (i < N_NODES) ? cnt[i] : 0;
        if (i < N_NODES) dinv[i] = rsqrtf((float)v + 1.0f);
        // wave-inclusive scan
        int s = v;
#pragma unroll
        for (int off = 1; off < 64; off <<= 1) {
            int u = __shfl_up(s, off);
            if (lane >= off) s += u;
        }
        if (lane == 63) wsum[wid] = s;
        __syncthreads();
        if (t < 16) {
            int a = wsum[t];
            int p = a;
#pragma unroll
            for (int off = 1; off < 16; off <<= 1) {
                int u = __shfl_up(p, off);
                if (t >= off) p += u;
            }
            wpre[t] = p - a;   // exclusive across waves
        }
        __syncthreads();
        int excl = s_running + wpre[wid] + (s - v);
        if (i < N_NODES) { offsets[i] = excl; cursor[i] = excl; }
        __syncthreads();                 // all reads of s_running done
        if (t == 1023) s_running = excl + v;
        __syncthreads();
    }
    if (t == 0) offsets[N_NODES] = s_running;   // == NEDGE
    for (int i = t; i < NB * F2; i += 1024) pool[i] = 0.0f;
}

__global__ void fill_kernel(const int* __restrict__ rows, const int* __restrict__ cols,
                            int* __restrict__ cursor, int* __restrict__ row_sorted) {
    int e = blockIdx.x * blockDim.x + threadIdx.x;
    if (e < NEDGE) {
        int pos = atomicAdd(&cursor[cols[e]], 1);
        row_sorted[pos] = rows[e];
    }
}

// ---------------------------------------------------------------------------
// CSC gather (aggregation-first form), 4 nodes per 256-thread block:
// wave w owns node c = blockIdx*4 + w entirely (no cross-wave comms).
//   out[c] = (src[c]*dinv[c] + sum_{r in N(c)} src[r]*dinv[r]) * dinv[c]
// RELU: apply relu to each loaded src element (for layer-2's relu(agg1)).
// lane owns one float4 of the 256-float row; 4-deep load unroll for MLP.
// ---------------------------------------------------------------------------
template <int C, bool RELU>
__global__ __launch_bounds__(256)
void gather_kernel(const float* __restrict__ src, const float* __restrict__ dinv,
                   const int* __restrict__ offsets, const int* __restrict__ row_sorted,
                   float* __restrict__ out) {
    const int c = blockIdx.x * 4 + (threadIdx.x >> 6);
    const int t = threadIdx.x & 63;               // float4 lane within the row
    if (c >= N_NODES) return;
    const float dc = dinv[c];

    float4 v = ((const float4*)(src + (size_t)c * C))[t];
    if (RELU) {
        v.x = fmaxf(v.x, 0.0f); v.y = fmaxf(v.y, 0.0f);
        v.z = fmaxf(v.z, 0.0f); v.w = fmaxf(v.w, 0.0f);
    }
    float4 acc;
    acc.x = v.x * dc; acc.y = v.y * dc; acc.z = v.z * dc; acc.w = v.w * dc;

    const int beg = offsets[c], end = offsets[c + 1];
    int j = beg;
    for (; j + 4 <= end; j += 4) {
        int r0 = row_sorted[j + 0];
        int r1 = row_sorted[j + 1];
        int r2 = row_sorted[j + 2];
        int r3 = row_sorted[j + 3];
        float d0 = dinv[r0], d1 = dinv[r1], d2 = dinv[r2], d3 = dinv[r3];
        float4 u0 = ((const float4*)(src + (size_t)r0 * C))[t];
        float4 u1 = ((const float4*)(src + (size_t)r1 * C))[t];
        float4 u2 = ((const float4*)(src + (size_t)r2 * C))[t];
        float4 u3 = ((const float4*)(src + (size_t)r3 * C))[t];
        if (RELU) {
            u0.x = fmaxf(u0.x, 0.0f); u0.y = fmaxf(u0.y, 0.0f);
            u0.z = fmaxf(u0.z, 0.0f); u0.w = fmaxf(u0.w, 0.0f);
            u1.x = fmaxf(u1.x, 0.0f); u1.y = fmaxf(u1.y, 0.0f);
            u1.z = fmaxf(u1.z, 0.0f); u1.w = fmaxf(u1.w, 0.0f);
            u2.x = fmaxf(u2.x, 0.0f); u2.y = fmaxf(u2.y, 0.0f);
            u2.z = fmaxf(u2.z, 0.0f); u2.w = fmaxf(u2.w, 0.0f);
            u3.x = fmaxf(u3.x, 0.0f); u3.y = fmaxf(u3.y, 0.0f);
            u3.z = fmaxf(u3.z, 0.0f); u3.w = fmaxf(u3.w, 0.0f);
        }
        acc.x = fmaf(u0.x, d0, acc.x); acc.y = fmaf(u0.y, d0, acc.y);
        acc.z = fmaf(u0.z, d0, acc.z); acc.w = fmaf(u0.w, d0, acc.w);
        acc.x = fmaf(u1.x, d1, acc.x); acc.y = fmaf(u1.y, d1, acc.y);
        acc.z = fmaf(u1.z, d1, acc.z); acc.w = fmaf(u1.w, d1, acc.w);
        acc.x = fmaf(u2.x, d2, acc.x); acc.y = fmaf(u2.y, d2, acc.y);
        acc.z = fmaf(u2.z, d2, acc.z); acc.w = fmaf(u2.w, d2, acc.w);
        acc.x = fmaf(u3.x, d3, acc.x); acc.y = fmaf(u3.y, d3, acc.y);
        acc.z = fmaf(u3.z, d3, acc.z); acc.w = fmaf(u3.w, d3, acc.w);
    }
    for (; j < end; ++j) {
        int r0 = row_sorted[j];
        float d0 = dinv[r0];
        float4 u0 = ((const float4*)(src + (size_t)r0 * C))[t];
        if (RELU) {
            u0.x = fmaxf(u0.x, 0.0f); u0.y = fmaxf(u0.y, 0.0f);
            u0.z = fmaxf(u0.z, 0.0f); u0.w = fmaxf(u0.w, 0.0f);
        }
        acc.x = fmaf(u0.x, d0, acc.x); acc.y = fmaf(u0.y, d0, acc.y);
        acc.z = fmaf(u0.z, d0, acc.z); acc.w = fmaf(u0.w, d0, acc.w);
    }

    float4 o;
    o.x = acc.x * dc; o.y = acc.y * dc; o.z = acc.z * dc; o.w = acc.w * dc;
    ((float4*)(out + (size_t)c * C))[t] = o;
}

// ---------------------------------------------------------------------------
// fp32 tiled GEMM:  BM=64 BN=256 BK=16, 256 threads, 4x16 acc per thread.
// EPI=0: C = A@W + bias                      (layer-1 output)
// EPI=1: pool[g][n] max= relu(A@W + bias)    (layer-2 fused with per-graph
//        max-pool; nothing stored to C — pool must be pre-zeroed)
// Requires M%64==0, N%256==0, K%16==0.
// ---------------------------------------------------------------------------
template <int EPI>
__global__ __launch_bounds__(256)
void gemm_kernel(const float* __restrict__ A, const float* __restrict__ W,
                 const float* __restrict__ bias, float* __restrict__ C,
                 unsigned int* __restrict__ pool, int M, int K, int N) {
    constexpr int BM = 64, BN = 256, BK = 16;
    __shared__ float As[BK][BM + 4];   // +4 pad keeps 16B align, breaks store conflicts
    __shared__ float Ws[BK][BN];

    const int t  = threadIdx.x;
    const int m0 = blockIdx.x * BM;
    const int n0 = blockIdx.y * BN;

    const int tr = (t >> 4) * 4;       // 4 output rows
    const int tc = (t & 15) * 4;       // cols tc + {0,64,128,192}

    float acc[4][16];
#pragma unroll
    for (int i = 0; i < 4; ++i)
#pragma unroll
        for (int j = 0; j < 16; ++j) acc[i][j] = 0.0f;

    // global load assignment
    const int la_row = t >> 2;          // 0..63
    const int la_col = (t & 3) * 4;     // 0,4,8,12
    const int lw_row = t >> 4;          // 0..15
    const int lw_col = (t & 15) * 4;    // 0..60 (+64/128/192)

    const float* Aptr = A + (size_t)(m0 + la_row) * K + la_col;
    const float* Wptr = W + (size_t)lw_row * N + n0 + lw_col;

    for (int k0 = 0; k0 < K; k0 += BK) {
        float4 av = *(const float4*)Aptr;  Aptr += BK;
        float4 wv0 = *(const float4*)(Wptr + 0);
        float4 wv1 = *(const float4*)(Wptr + 64);
        float4 wv2 = *(const float4*)(Wptr + 128);
        float4 wv3 = *(const float4*)(Wptr + 192);
        Wptr += (size_t)BK * N;

        As[la_col + 0][la_row] = av.x;
        As[la_col + 1][la_row] = av.y;
        As[la_col + 2][la_row] = av.z;
        As[la_col + 3][la_row] = av.w;
        *(float4*)&Ws[lw_row][lw_col +   0] = wv0;
        *(float4*)&Ws[lw_row][lw_col +  64] = wv1;
        *(float4*)&Ws[lw_row][lw_col + 128] = wv2;
        *(float4*)&Ws[lw_row][lw_col + 192] = wv3;
        __syncthreads();

#pragma unroll
        for (int k = 0; k < BK; ++k) {
            float4 a  = *(const float4*)&As[k][tr];
            float4 w0 = *(const float4*)&Ws[k][tc +   0];
            float4 w1 = *(const float4*)&Ws[k][tc +  64];
            float4 w2 = *(const float4*)&Ws[k][tc + 128];
            float4 w3 = *(const float4*)&Ws[k][tc + 192];
            float ar[4] = {a.x, a.y, a.z, a.w};
            float wr[16] = {w0.x, w0.y, w0.z, w0.w, w1.x, w1.y, w1.z, w1.w,
                            w2.x, w2.y, w2.z, w2.w, w3.x, w3.y, w3.z, w3.w};
#pragma unroll
            for (int i = 0; i < 4; ++i)
#pragma unroll
                for (int j = 0; j < 16; ++j)
                    acc[i][j] = fmaf(ar[i], wr[j], acc[i][j]);
        }
        __syncthreads();
    }

    // bias for this thread's 16 columns
    float bcol[16];
    {
        float4 b0 = *(const float4*)&bias[n0 + tc +   0];
        float4 b1 = *(const float4*)&bias[n0 + tc +  64];
        float4 b2 = *(const float4*)&bias[n0 + tc + 128];
        float4 b3 = *(const float4*)&bias[n0 + tc + 192];
        bcol[0]=b0.x; bcol[1]=b0.y; bcol[2]=b0.z; bcol[3]=b0.w;
        bcol[4]=b1.x; bcol[5]=b1.y; bcol[6]=b1.z; bcol[7]=b1.w;
        bcol[8]=b2.x; bcol[9]=b2.y; bcol[10]=b2.z; bcol[11]=b2.w;
        bcol[12]=b3.x; bcol[13]=b3.y; bcol[14]=b3.z; bcol[15]=b3.w;
    }

    if constexpr (EPI == 0) {
#pragma unroll
        for (int i = 0; i < 4; ++i) {
            size_t row = (size_t)(m0 + tr + i);
            float* cp = &C[row * N + n0 + tc];
            *(float4*)(cp +   0) = make_float4(acc[i][0]+bcol[0],  acc[i][1]+bcol[1],
                                               acc[i][2]+bcol[2],  acc[i][3]+bcol[3]);
            *(float4*)(cp +  64) = make_float4(acc[i][4]+bcol[4],  acc[i][5]+bcol[5],
                                               acc[i][6]+bcol[6],  acc[i][7]+bcol[7]);
            *(float4*)(cp + 128) = make_float4(acc[i][8]+bcol[8],  acc[i][9]+bcol[9],
                                               acc[i][10]+bcol[10],acc[i][11]+bcol[11]);
            *(float4*)(cp + 192) = make_float4(acc[i][12]+bcol[12],acc[i][13]+bcol[13],
                                               acc[i][14]+bcol[14],acc[i][15]+bcol[15]);
        }
    } else {
        // fused per-graph max-pool of relu(acc + bias); block spans <=2 graphs
        __shared__ unsigned int red[2][BN];
        for (int i = t; i < 2 * BN; i += 256) red[i >> 8][i & 255] = 0u;
        __syncthreads();

        const int g_lo = m0 / PROTS;
        const int slot_first = (m0 + tr) / PROTS - g_lo;
        const int slot_last  = (m0 + tr + 3) / PROTS - g_lo;

        if (slot_first == slot_last) {
            // all 4 rows in one graph: register-reduce then 16 LDS atomics
#pragma unroll
            for (int j = 0; j < 16; ++j) {
                float m = fmaxf(fmaxf(acc[0][j], acc[1][j]), fmaxf(acc[2][j], acc[3][j]));
                m = fmaxf(m + bcol[j], 0.0f);
                int lc = tc + (j >> 2) * 64 + (j & 3);
                atomicMax(&red[slot_first][lc], __float_as_uint(m));
            }
        } else {
#pragma unroll
            for (int i = 0; i < 4; ++i) {
                int slot = (m0 + tr + i) / PROTS - g_lo;
#pragma unroll
                for (int j = 0; j < 16; ++j) {
                    float m = fmaxf(acc[i][j] + bcol[j], 0.0f);
                    int lc = tc + (j >> 2) * 64 + (j & 3);
                    atomicMax(&red[slot][lc], __float_as_uint(m));
                }
            }
        }
        __syncthreads();

        const int straddle = ((m0 + BM - 1) / PROTS) != g_lo;
        for (int lc = t; lc < BN; lc += 256) {
            atomicMax(&pool[(size_t)g_lo * F2 + n0 + lc], red[0][lc]);
            if (straddle)
                atomicMax(&pool[(size_t)(g_lo + 1) * F2 + n0 + lc], red[1][lc]);
        }
    }
}

// ---------------------------------------------------------------------------
// g1 = relu(pool @ Wg1 + bg1)   [4,512]@[512,1028]
// ---------------------------------------------------------------------------
__global__ void mlpg1_kernel(const float* __restrict__ pool, const float* __restrict__ Wg1,
                             const float* __restrict__ bg1, float* __restrict__ out) {
    int idx = blockIdx.x * blockDim.x + threadIdx.x;
    if (idx >= NB * G1DIM) return;
    int b = idx / G1DIM, j = idx % G1DIM;
    const float* g = pool + b * F2;
    float s0 = 0.f, s1 = 0.f, s2 = 0.f, s3 = 0.f;
    for (int k = 0; k < F2; k += 4) {
        s0 = fmaf(g[k + 0], Wg1[(size_t)(k + 0) * G1DIM + j], s0);
        s1 = fmaf(g[k + 1], Wg1[(size_t)(k + 1) * G1DIM + j], s1);
        s2 = fmaf(g[k + 2], Wg1[(size_t)(k + 2) * G1DIM + j], s2);
        s3 = fmaf(g[k + 3], Wg1[(size_t)(k + 3) * G1DIM + j], s3);
    }
    out[idx] = fmaxf((s0 + s1) + (s2 + s3) + bg1[j], 0.0f);
}

// ---------------------------------------------------------------------------
// tail: g2 = g1@Wg2+bg2 ; z=[g2,DDI] ; f1=relu(z@Wf1+bf1) ;
//       f2=relu(f1@Wf2+bf2) ; out=sigmoid(f2@Wf3+bf3)      single block
// ---------------------------------------------------------------------------
__global__ __launch_bounds__(256)
void tail_kernel(const float* __restrict__ g1, const float* __restrict__ Wg2,
                 const float* __restrict__ bg2, const float* __restrict__ DDI,
                 const float* __restrict__ Wf1, const float* __restrict__ bf1,
                 const float* __restrict__ Wf2, const float* __restrict__ bf2,
                 const float* __restrict__ Wf3, const float* __restrict__ bf3,
                 float* __restrict__ out) {
    __shared__ float zs[NB][ZDIM + 8];
    __shared__ float f1s[NB][64];
    __shared__ float f2s[NB][16];
    int t = threadIdx.x;

    if (t < NB * G2DIM) {                      // 128 threads: g2
        int b = t >> 5, j = t & 31;
        float s0 = 0.f, s1 = 0.f, s2 = 0.f, s3 = 0.f;
        const float* gp = g1 + b * G1DIM;
        int k = 0;
        for (; k + 4 <= G1DIM; k += 4) {
            s0 = fmaf(gp[k + 0], Wg2[(size_t)(k + 0) * G2DIM + j], s0);
            s1 = fmaf(gp[k + 1], Wg2[(size_t)(k + 1) * G2DIM + j], s1);
            s2 = fmaf(gp[k + 2], Wg2[(size_t)(k + 2) * G2DIM + j], s2);
            s3 = fmaf(gp[k + 3], Wg2[(size_t)(k + 3) * G2DIM + j], s3);
        }
        for (; k < G1DIM; ++k) s0 = fmaf(gp[k], Wg2[(size_t)k * G2DIM + j], s0);
        zs[b][j] = (s0 + s1) + (s2 + s3) + bg2[j];
    }
    for (int i = t; i < NB * NDRUGS; i += 256) {
        int b = i / NDRUGS, k = i % NDRUGS;
        zs[b][G2DIM + k] = DDI[i];
    }
    __syncthreads();

    {   // f1: all 256 threads
        int b = t >> 6, j = t & 63;
        float s = bf1[j];
        for (int k = 0; k < ZDIM; ++k) s = fmaf(zs[b][k], Wf1[(size_t)k * 64 + j], s);
        f1s[b][j] = fmaxf(s, 0.0f);
    }
    __syncthreads();

    if (t < NB * 16) {
        int b = t >> 4, j = t & 15;
        float s = bf2[j];
#pragma unroll
        for (int k = 0; k < 64; ++k) s = fmaf(f1s[b][k], Wf2[k * 16 + j], s);
        f2s[b][j] = fmaxf(s, 0.0f);
    }
    __syncthreads();

    if (t < NB) {
        float s = bf3[0];
#pragma unroll
        for (int k = 0; k < 16; ++k) s = fmaf(f2s[t][k], Wf3[k], s);
        out[t] = 1.0f / (1.0f + expf(-s));
    }
}

// ---------------------------------------------------------------------------
// launch
// ---------------------------------------------------------------------------
extern "C" void kernel_launch(void* const* d_in, const int* in_sizes, int n_in,
                              void* d_out, int out_size, void* d_ws, size_t ws_size,
                              hipStream_t stream) {
    const float* x   = (const float*)d_in[0];
    const int*   ei  = (const int*)d_in[1];
    const float* DDI = (const float*)d_in[2];
    const float* W1  = (const float*)d_in[3];
    const float* b1  = (const float*)d_in[4];
    const float* W2  = (const float*)d_in[5];
    const float* b2  = (const float*)d_in[6];
    const float* Wg1 = (const float*)d_in[7];
    const float* bg1 = (const float*)d_in[8];
    const float* Wg2 = (const float*)d_in[9];
    const float* bg2 = (const float*)d_in[10];
    const float* Wf1 = (const float*)d_in[11];
    const float* bf1 = (const float*)d_in[12];
    const float* Wf2 = (const float*)d_in[13];
    const float* bf2 = (const float*)d_in[14];
    const float* Wf3 = (const float*)d_in[15];
    const float* bf3 = (const float*)d_in[16];
    float* out = (float*)d_out;

    const int* rows = ei;            // edge_index[0]
    const int* cols = ei + NEDGE;    // edge_index[1]

    // workspace layout
    char* ws = (char*)d_ws;
    const size_t MiB = 1024 * 1024;
    int*   cnt        = (int*)(ws + 0);            // 160 KB
    int*   offsets    = (int*)(ws + 256 * 1024);   // 160 KB (+1 elem)
    int*   cursor     = (int*)(ws + 512 * 1024);   // 160 KB
    float* dinv       = (float*)(ws + 768 * 1024); // 160 KB
    int*   row_sorted = (int*)(ws + 1 * MiB);      // 1.28 MB
    float* pool       = (float*)(ws + 2560 * 1024);// 8 KB
    float* g1o        = (float*)(ws + 2664 * 1024);// 16.4 KB
    float* xa   = (float*)(ws + 4 * MiB);          // 40.96 MB (aggregated x; later reused as ya)
    float* agg1 = (float*)(ws + 48 * MiB);         // 40.96 MB (ends ~88 MiB)
    float* ya   = xa;                              // xa dead after gemm1 -> reuse

    // CSC build (shared by both conv layers)
    zero_cnt_kernel<<<(N_NODES + 255) / 256, 256, 0, stream>>>(cnt);
    count_kernel<<<(NEDGE + 255) / 256, 256, 0, stream>>>(cols, cnt);
    scan_dinv_kernel<<<1, 1024, 0, stream>>>(cnt, offsets, cursor, dinv, pool);
    fill_kernel<<<(NEDGE + 255) / 256, 256, 0, stream>>>(rows, cols, cursor, row_sorted);

    // conv1, aggregation-first:  xa = A_hat x ;  agg1 = xa@W1 + b1
    gather_kernel<F1, false><<<N_NODES / 4, 256, 0, stream>>>(x, dinv, offsets, row_sorted, xa);
    gemm_kernel<0><<<dim3(N_NODES / 64, F1 / 256), 256, 0, stream>>>(
        xa, W1, b1, agg1, nullptr, N_NODES, F1, F1);

    // conv2, aggregation-first:  ya = A_hat relu(agg1) ;
    // pool[g][:] = max over rows of relu(ya@W2 + b2)   (fused epilogue)
    gather_kernel<F1, true><<<N_NODES / 4, 256, 0, stream>>>(agg1, dinv, offsets, row_sorted, ya);
    gemm_kernel<1><<<dim3(N_NODES / 64, F2 / 256), 256, 0, stream>>>(
        ya, W2, b2, nullptr, (unsigned int*)pool, N_NODES, F1, F2);

    // graph MLP + head
    mlpg1_kernel<<<(NB * G1DIM + 255) / 256, 256, 0, stream>>>(pool, Wg1, bg1, g1o);
    tail_kernel<<<1, 256, 0, stream>>>(g1o, Wg2, bg2, DDI, Wf1, bf1, Wf2, bf2, Wf3, bf3, out);
}

// Round 13
// 530.724 us; speedup vs baseline: 1.3116x; 1.0685x over previous
//
#include <hip/hip_runtime.h>
#include <hip/hip_bf16.h>
#include <hip/hip_fp16.h>
#include <math.h>

// Problem constants (fixed by reference)
#define N_NODES   40000
#define F1        256        // F_IN
#define F2        512        // F_OUT2
#define NEDGE     320000
#define NB        4          // batch (graphs)
#define PROTS     10000      // nodes per graph
#define G1DIM     1028
#define G2DIM     32
#define NDRUGS    640
#define ZDIM      (G2DIM + NDRUGS)   // 672

// ---------------------------------------------------------------------------
// CSC build: in-degree count -> exclusive scan -> bucket fill
// ---------------------------------------------------------------------------
__global__ void zero_cnt_kernel(int* __restrict__ cnt) {
    int i = blockIdx.x * blockDim.x + threadIdx.x;
    if (i < N_NODES) cnt[i] = 0;
}

__global__ void count_kernel(const int* __restrict__ cols, int* __restrict__ cnt) {
    int e = blockIdx.x * blockDim.x + threadIdx.x;
    if (e < NEDGE) atomicAdd(&cnt[cols[e]], 1);
}

// single block, 1024 threads: exclusive scan of cnt -> offsets & cursor,
// dinv = rsqrt(cnt+1), zero the pool buffer
__global__ __launch_bounds__(1024)
void scan_dinv_kernel(const int* __restrict__ cnt, int* __restrict__ offsets,
                      int* __restrict__ cursor, float* __restrict__ dinv,
                      float* __restrict__ pool) {
    __shared__ int wsum[16];
    __shared__ int wpre[16];
    __shared__ int s_running;
    int t = threadIdx.x, lane = t & 63, wid = t >> 6;
    if (t == 0) s_running = 0;
    __syncthreads();
    for (int base = 0; base < N_NODES; base += 1024) {
        int i = base + t;
        int v = (i < N_NODES) ? cnt[i] : 0;
        if (i < N_NODES) dinv[i] = rsqrtf((float)v + 1.0f);
        // wave-inclusive scan
        int s = v;
#pragma unroll
        for (int off = 1; off < 64; off <<= 1) {
            int u = __shfl_up(s, off);
            if (lane >= off) s += u;
        }
        if (lane == 63) wsum[wid] = s;
        __syncthreads();
        if (t < 16) {
            int a = wsum[t];
            int p = a;
#pragma unroll
            for (int off = 1; off < 16; off <<= 1) {
                int u = __shfl_up(p, off);
                if (t >= off) p += u;
            }
            wpre[t] = p - a;   // exclusive across waves
        }
        __syncthreads();
        int excl = s_running + wpre[wid] + (s - v);
        if (i < N_NODES) { offsets[i] = excl; cursor[i] = excl; }
        __syncthreads();                 // all reads of s_running done
        if (t == 1023) s_running = excl + v;
        __syncthreads();
    }
    if (t == 0) offsets[N_NODES] = s_running;   // == NEDGE
    for (int i = t; i < NB * F2; i += 1024) pool[i] = 0.0f;
}

__global__ void fill_kernel(const int* __restrict__ rows, const int* __restrict__ cols,
                            int* __restrict__ cursor, int* __restrict__ row_sorted) {
    int e = blockIdx.x * blockDim.x + threadIdx.x;
    if (e < NEDGE) {
        int pos = atomicAdd(&cursor[cols[e]], 1);
        row_sorted[pos] = rows[e];
    }
}

// ---------------------------------------------------------------------------
// fp32 -> fp16 convert (vectorized: float4 in, 4 halfs = 8B out)
// ---------------------------------------------------------------------------
__global__ void f32_to_f16_kernel(const float* __restrict__ in, __half* __restrict__ out,
                                  int n4) {
    int i = blockIdx.x * blockDim.x + threadIdx.x;
    if (i >= n4) return;
    float4 v = ((const float4*)in)[i];
    __half2 h01 = __float22half2_rn(make_float2(v.x, v.y));
    __half2 h23 = __float22half2_rn(make_float2(v.z, v.w));
    uint2 u;
    u.x = *reinterpret_cast<unsigned int*>(&h01);
    u.y = *reinterpret_cast<unsigned int*>(&h23);
    ((uint2*)out)[i] = u;
}

// ---------------------------------------------------------------------------
// load 4 consecutive fp16 features (8B) of a row, as float4
// ---------------------------------------------------------------------------
__device__ __forceinline__ float4 load4h(const __half* __restrict__ rowp, int t) {
    uint2 raw = ((const uint2*)rowp)[t];
    __half2 h01 = *reinterpret_cast<__half2*>(&raw.x);
    __half2 h23 = *reinterpret_cast<__half2*>(&raw.y);
    float2 f01 = __half22float2(h01);
    float2 f23 = __half22float2(h23);
    return make_float4(f01.x, f01.y, f23.x, f23.y);
}

// ---------------------------------------------------------------------------
// CSC gather (aggregation-first), fp16 input rows, fp32 output.
// 4 nodes per 256-thread block: wave w owns node c = blockIdx*4 + w.
//   out[c] = (src[c]*dinv[c] + sum_{r in N(c)} src[r]*dinv[r]) * dinv[c]
// (any relu is pre-applied at the producer, so none here)
// ---------------------------------------------------------------------------
template <int C>
__global__ __launch_bounds__(256)
void gather_kernel(const __half* __restrict__ src, const float* __restrict__ dinv,
                   const int* __restrict__ offsets, const int* __restrict__ row_sorted,
                   float* __restrict__ out) {
    const int c = blockIdx.x * 4 + (threadIdx.x >> 6);
    const int t = threadIdx.x & 63;               // 4-feature group within the row
    if (c >= N_NODES) return;
    const float dc = dinv[c];

    float4 v = load4h(src + (size_t)c * C, t);
    float4 acc;
    acc.x = v.x * dc; acc.y = v.y * dc; acc.z = v.z * dc; acc.w = v.w * dc;

    const int beg = offsets[c], end = offsets[c + 1];
    int j = beg;
    for (; j + 4 <= end; j += 4) {
        int r0 = row_sorted[j + 0];
        int r1 = row_sorted[j + 1];
        int r2 = row_sorted[j + 2];
        int r3 = row_sorted[j + 3];
        float d0 = dinv[r0], d1 = dinv[r1], d2 = dinv[r2], d3 = dinv[r3];
        float4 u0 = load4h(src + (size_t)r0 * C, t);
        float4 u1 = load4h(src + (size_t)r1 * C, t);
        float4 u2 = load4h(src + (size_t)r2 * C, t);
        float4 u3 = load4h(src + (size_t)r3 * C, t);
        acc.x = fmaf(u0.x, d0, acc.x); acc.y = fmaf(u0.y, d0, acc.y);
        acc.z = fmaf(u0.z, d0, acc.z); acc.w = fmaf(u0.w, d0, acc.w);
        acc.x = fmaf(u1.x, d1, acc.x); acc.y = fmaf(u1.y, d1, acc.y);
        acc.z = fmaf(u1.z, d1, acc.z); acc.w = fmaf(u1.w, d1, acc.w);
        acc.x = fmaf(u2.x, d2, acc.x); acc.y = fmaf(u2.y, d2, acc.y);
        acc.z = fmaf(u2.z, d2, acc.z); acc.w = fmaf(u2.w, d2, acc.w);
        acc.x = fmaf(u3.x, d3, acc.x); acc.y = fmaf(u3.y, d3, acc.y);
        acc.z = fmaf(u3.z, d3, acc.z); acc.w = fmaf(u3.w, d3, acc.w);
    }
    for (; j < end; ++j) {
        int r0 = row_sorted[j];
        float d0 = dinv[r0];
        float4 u0 = load4h(src + (size_t)r0 * C, t);
        acc.x = fmaf(u0.x, d0, acc.x); acc.y = fmaf(u0.y, d0, acc.y);
        acc.z = fmaf(u0.z, d0, acc.z); acc.w = fmaf(u0.w, d0, acc.w);
    }

    float4 o;
    o.x = acc.x * dc; o.y = acc.y * dc; o.z = acc.z * dc; o.w = acc.w * dc;
    ((float4*)(out + (size_t)c * C))[t] = o;
}

// ---------------------------------------------------------------------------
// fp32 tiled GEMM:  BM=64 BN=256 BK=16, 256 threads, 4x16 acc per thread.
// EPI=1: pool[g][n] max= relu(A@W + bias)    (layer-2, fused per-graph pool)
// EPI=2: Ch = fp16(relu(A@W + bias))         (layer-1, fp16+relu store)
// Requires M%64==0, N%256==0, K%16==0.
// ---------------------------------------------------------------------------
template <int EPI>
__global__ __launch_bounds__(256)
void gemm_kernel(const float* __restrict__ A, const float* __restrict__ W,
                 const float* __restrict__ bias, void* __restrict__ Cout,
                 unsigned int* __restrict__ pool, int M, int K, int N) {
    constexpr int BM = 64, BN = 256, BK = 16;
    __shared__ float As[BK][BM + 4];   // +4 pad keeps 16B align, breaks store conflicts
    __shared__ float Ws[BK][BN];

    const int t  = threadIdx.x;
    const int m0 = blockIdx.x * BM;
    const int n0 = blockIdx.y * BN;

    const int tr = (t >> 4) * 4;       // 4 output rows
    const int tc = (t & 15) * 4;       // cols tc + {0,64,128,192}

    float acc[4][16];
#pragma unroll
    for (int i = 0; i < 4; ++i)
#pragma unroll
        for (int j = 0; j < 16; ++j) acc[i][j] = 0.0f;

    // global load assignment
    const int la_row = t >> 2;          // 0..63
    const int la_col = (t & 3) * 4;     // 0,4,8,12
    const int lw_row = t >> 4;          // 0..15
    const int lw_col = (t & 15) * 4;    // 0..60 (+64/128/192)

    const float* Aptr = A + (size_t)(m0 + la_row) * K + la_col;
    const float* Wptr = W + (size_t)lw_row * N + n0 + lw_col;

    for (int k0 = 0; k0 < K; k0 += BK) {
        float4 av = *(const float4*)Aptr;  Aptr += BK;
        float4 wv0 = *(const float4*)(Wptr + 0);
        float4 wv1 = *(const float4*)(Wptr + 64);
        float4 wv2 = *(const float4*)(Wptr + 128);
        float4 wv3 = *(const float4*)(Wptr + 192);
        Wptr += (size_t)BK * N;

        As[la_col + 0][la_row] = av.x;
        As[la_col + 1][la_row] = av.y;
        As[la_col + 2][la_row] = av.z;
        As[la_col + 3][la_row] = av.w;
        *(float4*)&Ws[lw_row][lw_col +   0] = wv0;
        *(float4*)&Ws[lw_row][lw_col +  64] = wv1;
        *(float4*)&Ws[lw_row][lw_col + 128] = wv2;
        *(float4*)&Ws[lw_row][lw_col + 192] = wv3;
        __syncthreads();

#pragma unroll
        for (int k = 0; k < BK; ++k) {
            float4 a  = *(const float4*)&As[k][tr];
            float4 w0 = *(const float4*)&Ws[k][tc +   0];
            float4 w1 = *(const float4*)&Ws[k][tc +  64];
            float4 w2 = *(const float4*)&Ws[k][tc + 128];
            float4 w3 = *(const float4*)&Ws[k][tc + 192];
            float ar[4] = {a.x, a.y, a.z, a.w};
            float wr[16] = {w0.x, w0.y, w0.z, w0.w, w1.x, w1.y, w1.z, w1.w,
                            w2.x, w2.y, w2.z, w2.w, w3.x, w3.y, w3.z, w3.w};
#pragma unroll
            for (int i = 0; i < 4; ++i)
#pragma unroll
                for (int j = 0; j < 16; ++j)
                    acc[i][j] = fmaf(ar[i], wr[j], acc[i][j]);
        }
        __syncthreads();
    }

    // bias for this thread's 16 columns
    float bcol[16];
    {
        float4 b0 = *(const float4*)&bias[n0 + tc +   0];
        float4 b1 = *(const float4*)&bias[n0 + tc +  64];
        float4 b2 = *(const float4*)&bias[n0 + tc + 128];
        float4 b3 = *(const float4*)&bias[n0 + tc + 192];
        bcol[0]=b0.x; bcol[1]=b0.y; bcol[2]=b0.z; bcol[3]=b0.w;
        bcol[4]=b1.x; bcol[5]=b1.y; bcol[6]=b1.z; bcol[7]=b1.w;
        bcol[8]=b2.x; bcol[9]=b2.y; bcol[10]=b2.z; bcol[11]=b2.w;
        bcol[12]=b3.x; bcol[13]=b3.y; bcol[14]=b3.z; bcol[15]=b3.w;
    }

    if constexpr (EPI == 2) {
        // fp16 store with fused relu: r_h = fp16(relu(acc + bias))
        __half* Ch = (__half*)Cout;
#pragma unroll
        for (int i = 0; i < 4; ++i) {
            size_t row = (size_t)(m0 + tr + i);
            __half* cp = Ch + row * N + n0 + tc;
#pragma unroll
            for (int g = 0; g < 4; ++g) {
                float vx = fmaxf(acc[i][4*g + 0] + bcol[4*g + 0], 0.0f);
                float vy = fmaxf(acc[i][4*g + 1] + bcol[4*g + 1], 0.0f);
                float vz = fmaxf(acc[i][4*g + 2] + bcol[4*g + 2], 0.0f);
                float vw = fmaxf(acc[i][4*g + 3] + bcol[4*g + 3], 0.0f);
                __half2 h01 = __float22half2_rn(make_float2(vx, vy));
                __half2 h23 = __float22half2_rn(make_float2(vz, vw));
                uint2 u;
                u.x = *reinterpret_cast<unsigned int*>(&h01);
                u.y = *reinterpret_cast<unsigned int*>(&h23);
                *reinterpret_cast<uint2*>(cp + 64 * g) = u;
            }
        }
    } else {
        // EPI==1: fused per-graph max-pool of relu(acc + bias); block spans <=2 graphs
        __shared__ unsigned int red[2][BN];
        for (int i = t; i < 2 * BN; i += 256) red[i >> 8][i & 255] = 0u;
        __syncthreads();

        const int g_lo = m0 / PROTS;
        const int slot_first = (m0 + tr) / PROTS - g_lo;
        const int slot_last  = (m0 + tr + 3) / PROTS - g_lo;

        if (slot_first == slot_last) {
#pragma unroll
            for (int j = 0; j < 16; ++j) {
                float m = fmaxf(fmaxf(acc[0][j], acc[1][j]), fmaxf(acc[2][j], acc[3][j]));
                m = fmaxf(m + bcol[j], 0.0f);
                int lc = tc + (j >> 2) * 64 + (j & 3);
                atomicMax(&red[slot_first][lc], __float_as_uint(m));
            }
        } else {
#pragma unroll
            for (int i = 0; i < 4; ++i) {
                int slot = (m0 + tr + i) / PROTS - g_lo;
#pragma unroll
                for (int j = 0; j < 16; ++j) {
                    float m = fmaxf(acc[i][j] + bcol[j], 0.0f);
                    int lc = tc + (j >> 2) * 64 + (j & 3);
                    atomicMax(&red[slot][lc], __float_as_uint(m));
                }
            }
        }
        __syncthreads();

        const int straddle = ((m0 + BM - 1) / PROTS) != g_lo;
        for (int lc = t; lc < BN; lc += 256) {
            atomicMax(&pool[(size_t)g_lo * F2 + n0 + lc], red[0][lc]);
            if (straddle)
                atomicMax(&pool[(size_t)(g_lo + 1) * F2 + n0 + lc], red[1][lc]);
        }
    }
}

// ---------------------------------------------------------------------------
// g1 = relu(pool @ Wg1 + bg1)   [4,512]@[512,1028]
// ---------------------------------------------------------------------------
__global__ void mlpg1_kernel(const float* __restrict__ pool, const float* __restrict__ Wg1,
                             const float* __restrict__ bg1, float* __restrict__ out) {
    int idx = blockIdx.x * blockDim.x + threadIdx.x;
    if (idx >= NB * G1DIM) return;
    int b = idx / G1DIM, j = idx % G1DIM;
    const float* g = pool + b * F2;
    float s0 = 0.f, s1 = 0.f, s2 = 0.f, s3 = 0.f;
    for (int k = 0; k < F2; k += 4) {
        s0 = fmaf(g[k + 0], Wg1[(size_t)(k + 0) * G1DIM + j], s0);
        s1 = fmaf(g[k + 1], Wg1[(size_t)(k + 1) * G1DIM + j], s1);
        s2 = fmaf(g[k + 2], Wg1[(size_t)(k + 2) * G1DIM + j], s2);
        s3 = fmaf(g[k + 3], Wg1[(size_t)(k + 3) * G1DIM + j], s3);
    }
    out[idx] = fmaxf((s0 + s1) + (s2 + s3) + bg1[j], 0.0f);
}

// ---------------------------------------------------------------------------
// tail: g2 = g1@Wg2+bg2 ; z=[g2,DDI] ; f1=relu(z@Wf1+bf1) ;
//       f2=relu(f1@Wf2+bf2) ; out=sigmoid(f2@Wf3+bf3)      single block
// ---------------------------------------------------------------------------
__global__ __launch_bounds__(256)
void tail_kernel(const float* __restrict__ g1, const float* __restrict__ Wg2,
                 const float* __restrict__ bg2, const float* __restrict__ DDI,
                 const float* __restrict__ Wf1, const float* __restrict__ bf1,
                 const float* __restrict__ Wf2, const float* __restrict__ bf2,
                 const float* __restrict__ Wf3, const float* __restrict__ bf3,
                 float* __restrict__ out) {
    __shared__ float zs[NB][ZDIM + 8];
    __shared__ float f1s[NB][64];
    __shared__ float f2s[NB][16];
    int t = threadIdx.x;

    if (t < NB * G2DIM) {                      // 128 threads: g2
        int b = t >> 5, j = t & 31;
        float s0 = 0.f, s1 = 0.f, s2 = 0.f, s3 = 0.f;
        const float* gp = g1 + b * G1DIM;
        int k = 0;
        for (; k + 4 <= G1DIM; k += 4) {
            s0 = fmaf(gp[k + 0], Wg2[(size_t)(k + 0) * G2DIM + j], s0);
            s1 = fmaf(gp[k + 1], Wg2[(size_t)(k + 1) * G2DIM + j], s1);
            s2 = fmaf(gp[k + 2], Wg2[(size_t)(k + 2) * G2DIM + j], s2);
            s3 = fmaf(gp[k + 3], Wg2[(size_t)(k + 3) * G2DIM + j], s3);
        }
        for (; k < G1DIM; ++k) s0 = fmaf(gp[k], Wg2[(size_t)k * G2DIM + j], s0);
        zs[b][j] = (s0 + s1) + (s2 + s3) + bg2[j];
    }
    for (int i = t; i < NB * NDRUGS; i += 256) {
        int b = i / NDRUGS, k = i % NDRUGS;
        zs[b][G2DIM + k] = DDI[i];
    }
    __syncthreads();

    {   // f1: all 256 threads
        int b = t >> 6, j = t & 63;
        float s = bf1[j];
        for (int k = 0; k < ZDIM; ++k) s = fmaf(zs[b][k], Wf1[(size_t)k * 64 + j], s);
        f1s[b][j] = fmaxf(s, 0.0f);
    }
    __syncthreads();

    if (t < NB * 16) {
        int b = t >> 4, j = t & 15;
        float s = bf2[j];
#pragma unroll
        for (int k = 0; k < 64; ++k) s = fmaf(f1s[b][k], Wf2[k * 16 + j], s);
        f2s[b][j] = fmaxf(s, 0.0f);
    }
    __syncthreads();

    if (t < NB) {
        float s = bf3[0];
#pragma unroll
        for (int k = 0; k < 16; ++k) s = fmaf(f2s[t][k], Wf3[k], s);
        out[t] = 1.0f / (1.0f + expf(-s));
    }
}

// ---------------------------------------------------------------------------
// launch
// ---------------------------------------------------------------------------
extern "C" void kernel_launch(void* const* d_in, const int* in_sizes, int n_in,
                              void* d_out, int out_size, void* d_ws, size_t ws_size,
                              hipStream_t stream) {
    const float* x   = (const float*)d_in[0];
    const int*   ei  = (const int*)d_in[1];
    const float* DDI = (const float*)d_in[2];
    const float* W1  = (const float*)d_in[3];
    const float* b1  = (const float*)d_in[4];
    const float* W2  = (const float*)d_in[5];
    const float* b2  = (const float*)d_in[6];
    const float* Wg1 = (const float*)d_in[7];
    const float* bg1 = (const float*)d_in[8];
    const float* Wg2 = (const float*)d_in[9];
    const float* bg2 = (const float*)d_in[10];
    const float* Wf1 = (const float*)d_in[11];
    const float* bf1 = (const float*)d_in[12];
    const float* Wf2 = (const float*)d_in[13];
    const float* bf2 = (const float*)d_in[14];
    const float* Wf3 = (const float*)d_in[15];
    const float* bf3 = (const float*)d_in[16];
    float* out = (float*)d_out;

    const int* rows = ei;            // edge_index[0]
    const int* cols = ei + NEDGE;    // edge_index[1]

    // workspace layout
    char* ws = (char*)d_ws;
    const size_t MiB = 1024 * 1024;
    int*    cnt        = (int*)(ws + 0);            // 160 KB
    int*    offsets    = (int*)(ws + 256 * 1024);   // 160 KB (+1 elem)
    int*    cursor     = (int*)(ws + 512 * 1024);   // 160 KB
    float*  dinv       = (float*)(ws + 768 * 1024); // 160 KB
    int*    row_sorted = (int*)(ws + 1 * MiB);      // 1.28 MB
    float*  pool       = (float*)(ws + 2560 * 1024);// 8 KB
    float*  g1o        = (float*)(ws + 2664 * 1024);// 16.4 KB
    __half* x_h  = (__half*)(ws + 4 * MiB);         // 20.48 MB (ends ~24.5 MiB)
    float*  xa   = (float*)(ws + 26 * MiB);         // 40.96 MB (ends ~67 MiB)
    __half* r_h  = (__half*)(ws + 4 * MiB);         // reuses x_h region (dead after gather1)
    float*  ya   = (float*)(ws + 26 * MiB);         // reuses xa region (dead after gemm1)

    // CSC build (shared by both conv layers)
    zero_cnt_kernel<<<(N_NODES + 255) / 256, 256, 0, stream>>>(cnt);
    count_kernel<<<(NEDGE + 255) / 256, 256, 0, stream>>>(cols, cnt);
    scan_dinv_kernel<<<1, 1024, 0, stream>>>(cnt, offsets, cursor, dinv, pool);
    fill_kernel<<<(NEDGE + 255) / 256, 256, 0, stream>>>(rows, cols, cursor, row_sorted);

    // conv1, aggregation-first with fp16 gather operands:
    //   x_h = fp16(x) ; xa = A_hat x_h ; r_h = fp16(relu(xa@W1 + b1))
    f32_to_f16_kernel<<<(N_NODES * (F1 / 4) + 255) / 256, 256, 0, stream>>>(x, x_h, N_NODES * (F1 / 4));
    gather_kernel<F1><<<N_NODES / 4, 256, 0, stream>>>(x_h, dinv, offsets, row_sorted, xa);
    gemm_kernel<2><<<dim3(N_NODES / 64, F1 / 256), 256, 0, stream>>>(
        xa, W1, b1, (void*)r_h, nullptr, N_NODES, F1, F1);

    // conv2:  ya = A_hat r_h  (relu pre-applied) ;
    // pool[g][:] = max over rows of relu(ya@W2 + b2)   (fused epilogue)
    gather_kernel<F1><<<N_NODES / 4, 256, 0, stream>>>(r_h, dinv, offsets, row_sorted, ya);
    gemm_kernel<1><<<dim3(N_NODES / 64, F2 / 256), 256, 0, stream>>>(
        ya, W2, b2, nullptr, (unsigned int*)pool, N_NODES, F1, F2);

    // graph MLP + head
    mlpg1_kernel<<<(NB * G1DIM + 255) / 256, 256, 0, stream>>>(pool, Wg1, bg1, g1o);
    tail_kernel<<<1, 256, 0, stream>>>(g1o, Wg2, bg2, DDI, Wf1, bf1, Wf2, bf2, Wf3, bf3, out);
}